// Round 6
// baseline (1752.571 us; speedup 1.0000x reference)
//
// Persistent cooperative LSTM kernel for MI355X (gfx950) — round 14.
//  - R11 base (chunked exchange layout, 1740 µs). mm_pipe2 shelved (R13:
//    neutral). Two-level R3 barrier (R12: single-level = -327 µs, atomic
//    contention).
//  - NEW: rotating h/relu regions moved to a STATIC __device__ buffer
//    (28.25 MB .bss) — the cached-read + rotating-region path now ALWAYS
//    runs, independent of ws_size. Since R10 this path was gated on
//    ws_size >= 28.3 MB and we never confirmed it ran; if the coherent
//    fallback is what we've been measuring, mm reads (12.6 GB/dispatch)
//    are served by Infinity Cache (~7.5 TB/s sustained = the per-phase
//    floor). Cached plain loads let the 32 blocks of each XCD share one
//    L2 fill per line: same traffic at L2's ~34.5 TB/s aggregate.
//  - Correctness (unconditional rotation): each region is written (sc0 sc1
//    write-through, vmcnt-drained before gbar) strictly before its first
//    read within the dispatch; rotation => reading XCD has no prior-touch
//    line for the address; cross-dispatch staleness covered by the
//    kernel-boundary acquire invalidate (mechanism proven by R8's relub
//    final pass: plain loads of sc0sc1-rewritten data across dispatches).
//  - 256 blocks x 256 threads, 1 block/CU, 4 waves = K-quarters.
//    absmax canary: 0.0009765625 exactly.
#include <hip/hip_runtime.h>

typedef __attribute__((ext_vector_type(8))) short short8;
typedef __attribute__((ext_vector_type(4))) float float4_;
typedef unsigned long long u64;
typedef __attribute__((ext_vector_type(2))) unsigned long long u64x2;

#define AGENT __HIP_MEMORY_SCOPE_AGENT

// 226 regions x 131072 B: h0 g=-1..95 | h1 g=-1..95 | relu t=0..31
__device__ __attribute__((aligned(4096))) unsigned long long gws_static[3702784];

__device__ __forceinline__ unsigned short f2bf(float f) {
    unsigned u = __builtin_bit_cast(unsigned, f);
    u = (u + 0x7FFFu + ((u >> 16) & 1u)) >> 16;
    return (unsigned short)u;
}
__device__ __forceinline__ float bf2f(unsigned short h) {
    unsigned u = ((unsigned)h) << 16;
    return __builtin_bit_cast(float, u);
}
__device__ __forceinline__ float sigm(float x) { return 1.0f / (1.0f + __expf(-x)); }
__device__ __forceinline__ float tanhf_(float x) {
    x = fminf(fmaxf(x, -15.0f), 15.0f);
    float e = __expf(2.0f * x);
    return (e - 1.0f) / (e + 1.0f);
}

// coherent 8B store (write-through to coherence point)
__device__ __forceinline__ void st8_coh(unsigned short* p, unsigned long long v) {
    asm volatile("global_store_dwordx2 %0, %1, off sc0 sc1" :: "v"(p), "v"(v) : "memory");
}

// ---- grid barrier (R3-verbatim two-level): release = vmcnt drain of the
// write-through stores; 16 group counters (parallel lines) + root ----
__device__ __forceinline__ void gbar(unsigned* bar, unsigned target, int grpId) {
    asm volatile("s_waitcnt vmcnt(0)" ::: "memory");
    __syncthreads();
    if (threadIdx.x == 0) {
        unsigned old = __hip_atomic_fetch_add(bar + 256 + grpId * 16, 1u, __ATOMIC_RELAXED, AGENT);
        if ((old & 15u) == 15u) {
            unsigned old2 = __hip_atomic_fetch_add(bar + 512, 1u, __ATOMIC_RELAXED, AGENT);
            if ((old2 & 15u) == 15u) {
#pragma unroll
                for (int g = 0; g < 16; g++)
                    __hip_atomic_store(bar + g * 16, target, __ATOMIC_RELAXED, AGENT);
            }
        }
        while (__hip_atomic_load(bar + grpId * 16, __ATOMIC_RELAXED, AGENT) < target)
            __builtin_amdgcn_s_sleep(2);
    }
    __syncthreads();
}

__device__ __forceinline__ void zero4(float4_ (&a)[4]) {
    float4_ z;
    z[0] = 0.f; z[1] = 0.f; z[2] = 0.f; z[3] = 0.f;
#pragma unroll
    for (int i = 0; i < 4; i++) a[i] = z;
}

// ---- pipelined chunked staging, plain cached loads ----
#define LD2P(dst, base, OFF) \
    asm volatile("global_load_dwordx2 %0, %1, off offset:" #OFF \
                 : "=v"(dst) : "v"(base))

// 8 chunk-base pointers for one A matrix (chunked [256ch][64b][4u] bf16)
#define BASES8(P, A) \
    const char* P##0 = (const char*)(A) + q * 32768 + (lane >> 4) * 1024 + (lane & 15) * 8; \
    const char* P##1 = P##0 + 4096;  const char* P##2 = P##0 + 8192; \
    const char* P##3 = P##0 + 12288; const char* P##4 = P##0 + 16384; \
    const char* P##5 = P##0 + 20480; const char* P##6 = P##0 + 24576; \
    const char* P##7 = P##0 + 28672;

// 16 loads = one batch-tile (mt): 8 s-blocks x {lo,hi} chunk halves.
#define ISSUE16P(LO, HI, LD, P, O0, O1) \
    do { LD(LO[0], P##0, O0); LD(LO[1], P##1, O0); LD(LO[2], P##2, O0); \
         LD(LO[3], P##3, O0); LD(LO[4], P##4, O0); LD(LO[5], P##5, O0); \
         LD(LO[6], P##6, O0); LD(LO[7], P##7, O0); \
         LD(HI[0], P##0, O1); LD(HI[1], P##1, O1); LD(HI[2], P##2, O1); \
         LD(HI[3], P##3, O1); LD(HI[4], P##4, O1); LD(HI[5], P##5, O1); \
         LD(HI[6], P##6, O1); LD(HI[7], P##7, O1); } while (0)

#define WAITV16(N, LO, HI) \
    asm volatile("s_waitcnt vmcnt(" #N ")" \
                 : "+v"(LO[0]), "+v"(LO[1]), "+v"(LO[2]), "+v"(LO[3]), \
                   "+v"(LO[4]), "+v"(LO[5]), "+v"(LO[6]), "+v"(LO[7]), \
                   "+v"(HI[0]), "+v"(HI[1]), "+v"(HI[2]), "+v"(HI[3]), \
                   "+v"(HI[4]), "+v"(HI[5]), "+v"(HI[6]), "+v"(HI[7]))

#define MFMA8C(LO, HI, BF, ACCI) \
    do { _Pragma("unroll") \
         for (int s_ = 0; s_ < 8; s_++) { \
             u64x2 t_; t_[0] = LO[s_]; t_[1] = HI[s_]; \
             ACCI = __builtin_amdgcn_mfma_f32_16x16x32_bf16( \
                 __builtin_bit_cast(short8, t_), BF[s_], ACCI, 0, 0, 0); } } while (0)

// A chunked [256 chunks][64 b][4 u] bf16. A-frag: m = lane&15 (+16*mt),
// k = q*256 + (lane>>4)*8 + s*32 + j. Chunk pair for (s): bases[s], +512.
// Pipelined: 2-deep rotating 16-load batches, partial vmcnt(16) waits.
// Self-contained: starts at vmcnt==0, ends with WAITV16(0).
__device__ __forceinline__ void mm_pipe(const unsigned short* __restrict__ A,
                                        int q, int lane,
                                        const short8 (&bf)[8], float4_ (&acc)[4]) {
    BASES8(p_, A)
    u64 loA[8], hiA[8], loB[8], hiB[8];
    ISSUE16P(loA, hiA, LD2P, p_, 0, 512);
    ISSUE16P(loB, hiB, LD2P, p_, 128, 640);
    WAITV16(16, loA, hiA); MFMA8C(loA, hiA, bf, acc[0]);
    ISSUE16P(loA, hiA, LD2P, p_, 256, 768);
    WAITV16(16, loB, hiB); MFMA8C(loB, hiB, bf, acc[1]);
    ISSUE16P(loB, hiB, LD2P, p_, 384, 896);
    WAITV16(16, loA, hiA); MFMA8C(loA, hiA, bf, acc[2]);
    WAITV16(0, loB, hiB);  MFMA8C(loB, hiB, bf, acc[3]);
}

// C[m][n]: n = lane&15, m = quad*4+reg  -> gp[(q*64+row)*17+col]
__device__ __forceinline__ void write_parts(float* gp, int q, int lane, float4_ (&acc)[4]) {
    const int col = lane & 15;
    const int rbase = (lane >> 4) * 4;
#pragma unroll
    for (int mt = 0; mt < 4; mt++)
#pragma unroll
        for (int r = 0; r < 4; r++)
            gp[(q * 64 + mt * 16 + rbase + r) * 17 + col] = acc[mt][r];
}

__device__ __forceinline__ float gsum(const float* gp, int b, int c) {
    return gp[(0 * 64 + b) * 17 + c] + gp[(1 * 64 + b) * 17 + c] +
           gp[(2 * 64 + b) * 17 + c] + gp[(3 * 64 + b) * 17 + c];
}

__device__ __forceinline__ short8 packrow(const float* __restrict__ p) {
    short8 r;
#pragma unroll
    for (int j = 0; j < 8; j++) r[j] = (short)f2bf(p[j]);
    return r;
}

__global__ void __launch_bounds__(256, 1)
lstm_core(const float* __restrict__ x, const float* __restrict__ lastp,
          const float* __restrict__ Wih0, const float* __restrict__ Whh0,
          const float* __restrict__ bih0, const float* __restrict__ bhh0,
          const float* __restrict__ Wih1, const float* __restrict__ Whh1,
          const float* __restrict__ bih1, const float* __restrict__ bhh1,
          const float* __restrict__ W1, const float* __restrict__ b1,
          const float* __restrict__ W2, const float* __restrict__ b2,
          float* __restrict__ out, unsigned char* __restrict__ wsb)
{
    const int tid = threadIdx.x;
    const int blk = blockIdx.x;
    const int lane = tid & 63;
    const int q = tid >> 6;          // wave id = K quarter
    const int grpId = blk & 15;
    const int eb = tid >> 2;         // epilogue: batch row
    const int eu = tid & 3;          // epilogue: unit-within-block
    const int D_ = blk * 4 + eu;     // global hidden unit / fc dim

    unsigned* bar = (unsigned*)wsb;
    // rotating regions in static device memory: 97 + 97 + 32 x 131072 B
    unsigned short* h0base = (unsigned short*)gws_static;
    unsigned short* h1base = h0base + (size_t)97 * 65536;
    unsigned short* relub  = h0base + (size_t)194 * 65536;

    auto h0p = [&](int g) -> unsigned short* {
        return h0base + (size_t)(g + 1) * 65536;
    };
    auto h1p = [&](int g) -> unsigned short* {
        return h1base + (size_t)(g + 1) * 65536;
    };

    __shared__ float gparts[4 * 64 * 17];
    __shared__ float xlds[64 * 21];
    __shared__ float wih0l[16 * 20];
    __shared__ unsigned long long hstage_u64[64];
    unsigned short* hstage = (unsigned short*)hstage_u64;

    // ---- barrier area init (block 0) ----
    if (blk == 0 && tid == 0) {
        for (int g = 0; g < 16; g++) {
            __hip_atomic_store(bar + g * 16, 0u, __ATOMIC_RELAXED, AGENT);
            __hip_atomic_store(bar + 256 + g * 16, 0u, __ATOMIC_RELAXED, AGENT);
        }
        __hip_atomic_store(bar + 512, 0u, __ATOMIC_RELAXED, AGENT);
        __hip_atomic_store(bar + 544, 0x1357BDFu, __ATOMIC_RELEASE, AGENT);
    }

    // ---- per-lane B-fragment preload (bf16, RNE) ----
    const int n_ = lane & 15;
    const int gq_ = n_ >> 2, uu_ = n_ & 3;
    const int growL = gq_ * 1024 + blk * 4 + uu_;   // gate row for this col
    const int kq = (q << 8) + ((lane >> 4) << 3);

    short8 whh0f[8], wih1f[8], whh1f[8], wfusedf[8], wfcf[8];
#pragma unroll
    for (int s = 0; s < 8; s++) {
        const int k = kq + s * 32;
        whh0f[s] = packrow(Whh0 + growL * 1024 + k);
        wih1f[s] = packrow(Wih1 + growL * 1024 + k);
        whh1f[s] = packrow(Whh1 + growL * 1024 + k);
        { // Wfused[row][k] = sum_m Wih0[row][m] * W2[m][k]
            float a8[8] = {0.f, 0.f, 0.f, 0.f, 0.f, 0.f, 0.f, 0.f};
            for (int m = 0; m < 20; m++) {
                float wv = Wih0[growL * 20 + m];
                const float* w2p = W2 + m * 1024 + k;
#pragma unroll
                for (int j = 0; j < 8; j++) a8[j] += wv * w2p[j];
            }
            short8 r;
#pragma unroll
            for (int j = 0; j < 8; j++) r[j] = (short)f2bf(a8[j]);
            wfusedf[s] = r;
        }
        { // fc B: cols 0-3 = W1h rows, cols 4-7 = Wskip rows, 8-15 = 0
            short8 r;
            if (n_ < 4) {
                r = packrow(W1 + (blk * 4 + n_) * 1040 + k);
            } else if (n_ < 8) {
                const int D = blk * 4 + (n_ - 4);
                float a8[8] = {0.f, 0.f, 0.f, 0.f, 0.f, 0.f, 0.f, 0.f};
                for (int g2 = 0; g2 < 16; g2++) {
                    const int m = 5 * (g2 >> 2) + (g2 & 3);
                    float wv = W1[D * 1040 + 1024 + g2] * 0.01f;
                    const float* w2p = W2 + m * 1024 + k;
#pragma unroll
                    for (int j = 0; j < 8; j++) a8[j] += wv * w2p[j];
                }
#pragma unroll
                for (int j = 0; j < 8; j++) r[j] = (short)f2bf(a8[j]);
            } else {
#pragma unroll
                for (int j = 0; j < 8; j++) r[j] = 0;
            }
            wfcf[s] = r;
        }
    }

    // ---- per-thread constants (epilogue mapping: eb = tid>>2, eu = tid&3) ----
    float bias0g[4], bias1g[4], cgv[4];
#pragma unroll
    for (int g = 0; g < 4; g++) {
        const int row = g * 1024 + D_;
        bias0g[g] = bih0[row] + bhh0[row];
        bias1g[g] = bih1[row] + bhh1[row];
        float s = 0.f;
        for (int m = 0; m < 20; m++) s += Wih0[row * 20 + m] * b2[m];
        cgv[g] = s;
    }
    const float fcb = b1[D_];
    float cbv = 0.f, ustate = 0.f;
    for (int g2 = 0; g2 < 16; g2++) {
        const float w1v = W1[D_ * 1040 + 1024 + g2];
        cbv += b2[5 * (g2 >> 2) + (g2 & 3)] * w1v * 0.01f;
        ustate += lastp[eb * 16 + g2] * w1v;   // u(0) = lp0 @ W1lp^T
    }
    float c0v = 0.f, c1v = 0.f;

    if (tid < 16) { // Wih0 rows for x-path (fp32, exact)
        const int row = (tid >> 2) * 1024 + blk * 4 + (tid & 3);
        for (int m = 0; m < 20; m++) wih0l[tid * 20 + m] = Wih0[row * 20 + m];
    }
    // zero initial h state (g = -1); chunked: chunk blk, batch tid
    if (tid < 64) {
        st8_coh(h0p(-1) + blk * 256 + tid * 4, 0ull);
        st8_coh(h1p(-1) + blk * 256 + tid * 4, 0ull);
    }

    if (tid == 0) {
        while (__hip_atomic_load(bar + 544, __ATOMIC_RELAXED, AGENT) != 0x1357BDFu)
            __builtin_amdgcn_s_sleep(2);
    }
    unsigned tgt = 1;
    gbar(bar, tgt++, grpId);

    // ---- phase lambdas (R3-verbatim epilogues; chunked publish) ----
    auto stage_and_store = [&](unsigned short* dst, unsigned short val) {
        hstage[tid] = val;           // hstage[eb*4+eu] == hstage[tid]
        __syncthreads();
        if (tid < 64)                // chunk blk, batch tid: 512B contiguous
            st8_coh(dst + blk * 256 + tid * 4, hstage_u64[tid]);
    };

    auto do_l0 = [&](const unsigned short* h0prev, unsigned short* h0dst,
                     const unsigned short* reluprev, int xt) {
        if (xt >= 0) {  // stage x BEFORE the pipelined mm (vmcnt accounting)
            for (int i = tid; i < 1280; i += 256) {
                const int bb = i / 20, mm = i - bb * 20;
                xlds[bb * 21 + mm] = x[bb * 1280 + xt * 20 + mm];
            }
            asm volatile("s_waitcnt vmcnt(0)" ::: "memory");
        }
        float4_ acc[4];
        zero4(acc);
        mm_pipe(h0prev, q, lane, whh0f, acc);
        if (reluprev) mm_pipe(reluprev, q, lane, wfusedf, acc);
        write_parts(gparts, q, lane, acc);
        __syncthreads();
        float gv[4];
#pragma unroll
        for (int g = 0; g < 4; g++) gv[g] = gsum(gparts, eb, g * 4 + eu) + bias0g[g];
        if (xt >= 0) {
#pragma unroll
            for (int g = 0; g < 4; g++) {
                float s = 0.f;
                const float* wr = &wih0l[(g * 4 + eu) * 20];
                const float* xr = &xlds[eb * 21];
                for (int m = 0; m < 20; m++) s += xr[m] * wr[m];
                gv[g] += s;
            }
        } else {
#pragma unroll
            for (int g = 0; g < 4; g++) gv[g] += cgv[g];
        }
        const float iv = sigm(gv[0]), fv = sigm(gv[1]);
        const float gt = tanhf_(gv[2]), ov = sigm(gv[3]);
        c0v = fv * c0v + iv * gt;
        stage_and_store(h0dst, f2bf(ov * tanhf_(c0v)));
    };

    auto do_l1 = [&](const unsigned short* h0cur, const unsigned short* h1prev,
                     unsigned short* h1dst) {
        float4_ acc[4];
        zero4(acc);
        mm_pipe(h0cur, q, lane, wih1f, acc);
        mm_pipe(h1prev, q, lane, whh1f, acc);
        write_parts(gparts, q, lane, acc);
        __syncthreads();
        float gv[4];
#pragma unroll
        for (int g = 0; g < 4; g++) gv[g] = gsum(gparts, eb, g * 4 + eu) + bias1g[g];
        const float iv = sigm(gv[0]), fv = sigm(gv[1]);
        const float gt = tanhf_(gv[2]), ov = sigm(gv[3]);
        c1v = fv * c1v + iv * gt;
        stage_and_store(h1dst, f2bf(ov * tanhf_(c1v)));
    };

    auto do_fc = [&](int t, const unsigned short* h1cur, const unsigned short* reluprev) {
        float4_ acc1[4], acc2[4];
        zero4(acc1);
        zero4(acc2);
        mm_pipe(h1cur, q, lane, wfcf, acc1);              // cols 0-3: W1h@h1
        if (reluprev) mm_pipe(reluprev, q, lane, wfcf, acc2); // cols 4-7
        {
            const int col = lane & 15;
            const int rbase = (lane >> 4) * 4;
            if (col < 8) {
#pragma unroll
                for (int mt = 0; mt < 4; mt++)
#pragma unroll
                    for (int r = 0; r < 4; r++) {
                        const float v = (col < 4) ? acc1[mt][r] : acc2[mt][r];
                        gparts[(q * 64 + mt * 16 + rbase + r) * 17 + col] = v;
                    }
            }
        }
        __syncthreads();
        const float s1 = gsum(gparts, eb, eu);
        if (t > 0) ustate += gsum(gparts, eb, 4 + eu) + cbv;
        const float rv = fmaxf(s1 + ustate + fcb, 0.f);
        stage_and_store(relub + t * 65536, f2bf(rv));
    };

    // ---- encoder: 64 steps x {L0, barrier, L1} (post-L1 barrier elided) ----
    for (int g = 0; g < 64; g++) {
        do_l0(h0p(g - 1), h0p(g), nullptr, g);
        gbar(bar, tgt++, grpId);
        do_l1(h0p(g), h1p(g - 1), h1p(g));
    }
    // ---- decoder: 32 steps x {L0, b, L1, b, FC, b} ----
    for (int t = 0; t < 32; t++) {
        const int g = 64 + t;
        const unsigned short* rp = (t > 0) ? (relub + (t - 1) * 65536) : nullptr;
        do_l0(h0p(g - 1), h0p(g), rp, (t == 0) ? 63 : -1);
        gbar(bar, tgt++, grpId);
        do_l1(h0p(g), h1p(g - 1), h1p(g));
        gbar(bar, tgt++, grpId);
        do_fc(t, h1p(g), rp);
        gbar(bar, tgt++, grpId);
    }

    // ---- final: pred[t] = relu[t] @ W2^T + b2 -> out[b][t][m] ----
    {
        const int pj = tid >> 5;   // 8 (t,b) pairs per block
        const int m = tid & 31;
        if (m < 20) {
            const int pidx = blk * 8 + pj;
            const int tt = pidx >> 6, bb = pidx & 63;
            const unsigned short* rr = relub + tt * 65536;  // chunked region
            const float* w = W2 + m * 1024;
            float acc = 0.f;
            for (int c = 0; c < 256; c++) {
                const u64 v8 = *(const u64*)(rr + c * 256 + bb * 4);
#pragma unroll
                for (int j = 0; j < 4; j++)
                    acc += bf2f((unsigned short)(v8 >> (16 * j))) * w[c * 4 + j];
            }
            out[bb * 640 + tt * 20 + m] = acc + b2[m];
        }
    }
}

extern "C" void kernel_launch(void* const* d_in, const int* in_sizes, int n_in,
                              void* d_out, int out_size, void* d_ws, size_t ws_size,
                              hipStream_t stream) {
    (void)in_sizes; (void)n_in; (void)out_size; (void)ws_size;
    const float* x     = (const float*)d_in[0];
    const float* lastp = (const float*)d_in[1];
    const float* Wih0  = (const float*)d_in[2];
    const float* Whh0  = (const float*)d_in[3];
    const float* bih0  = (const float*)d_in[4];
    const float* bhh0  = (const float*)d_in[5];
    const float* Wih1  = (const float*)d_in[6];
    const float* Whh1  = (const float*)d_in[7];
    const float* bih1  = (const float*)d_in[8];
    const float* bhh1  = (const float*)d_in[9];
    const float* W1    = (const float*)d_in[10];
    const float* b1    = (const float*)d_in[11];
    const float* W2    = (const float*)d_in[12];
    const float* b2    = (const float*)d_in[13];
    float* out = (float*)d_out;
    unsigned char* ws = (unsigned char*)d_ws;

    void* args[] = {&x, &lastp, &Wih0, &Whh0, &bih0, &bhh0, &Wih1, &Whh1,
                    &bih1, &bhh1, &W1, &b1, &W2, &b2, &out, &ws};
    hipError_t err = hipLaunchCooperativeKernel((const void*)lstm_core,
                                                dim3(256), dim3(256), args, 0, stream);
    if (err != hipSuccess) {
        hipLaunchKernelGGL(lstm_core, dim3(256), dim3(256), 0, stream,
                           x, lastp, Wih0, Whh0, bih0, bhh0, Wih1, Whh1,
                           bih1, bhh1, W1, b1, W2, b2, out, ws);
    }
}

// Round 7
// 1411.713 us; speedup vs baseline: 1.2414x; 1.2414x over previous
//
// Persistent cooperative LSTM kernel for MI355X (gfx950) — round 15.
//  - Base = R14 (chunked exchange, static rotating regions, cached reads,
//    R3 two-level barrier). R13/R14 nulls established: read tier and mm
//    latency are NOT critical; residual ~1100 µs = publish-drain + barrier
//    consensus + skew (160 barriers, 224 phases).
//  - NEW 1: direct per-thread publish (global_store_short sc0 sc1, 64
//    lanes x 2B contiguous = 1 full line per wave). Removes the LDS stage
//    + extra __syncthreads from every phase. Same bytes, same addresses.
//  - NEW 2: x double-buffer prefetch (xlds[2]); encoder stages x[t+1]
//    during t's epilogue (drained by the next gbar). Removes an exposed
//    global RT + vmcnt(0) from the front of 65 phases. Decoder t=0 reuses
//    resident x[63].
//  - NEW 3: decoder fuzzy barriers: gbar split into arrive/wait; the wait
//    is filled with hoisted mm work on >=2-barrier-old (rotation-immutable,
//    L2-hot) operands: FC's Wskip@relu[t-1] (separate acc => order-free)
//    in the L0-slot wait; next L0's Whh0@h0[t] (first in acc order =>
//    order-preserved) in the FC-slot wait. L1 stays fully fresh (hoist
//    would swap accumulation order). Barrier protocol itself unchanged.
//  - All math order preserved => absmax canary must stay 0.0009765625.
//  - 256 blocks x 256 threads, 1 block/CU, 4 waves = K-quarters.
#include <hip/hip_runtime.h>

typedef __attribute__((ext_vector_type(8))) short short8;
typedef __attribute__((ext_vector_type(4))) float float4_;
typedef unsigned long long u64;
typedef __attribute__((ext_vector_type(2))) unsigned long long u64x2;

#define AGENT __HIP_MEMORY_SCOPE_AGENT

// 226 regions x 131072 B: h0 g=-1..95 | h1 g=-1..95 | relu t=0..31
__device__ __attribute__((aligned(4096))) unsigned long long gws_static[3702784];

__device__ __forceinline__ unsigned short f2bf(float f) {
    unsigned u = __builtin_bit_cast(unsigned, f);
    u = (u + 0x7FFFu + ((u >> 16) & 1u)) >> 16;
    return (unsigned short)u;
}
__device__ __forceinline__ float bf2f(unsigned short h) {
    unsigned u = ((unsigned)h) << 16;
    return __builtin_bit_cast(float, u);
}
__device__ __forceinline__ float sigm(float x) { return 1.0f / (1.0f + __expf(-x)); }
__device__ __forceinline__ float tanhf_(float x) {
    x = fminf(fmaxf(x, -15.0f), 15.0f);
    float e = __expf(2.0f * x);
    return (e - 1.0f) / (e + 1.0f);
}

// coherent stores (write-through to coherence point)
__device__ __forceinline__ void st8_coh(unsigned short* p, unsigned long long v) {
    asm volatile("global_store_dwordx2 %0, %1, off sc0 sc1" :: "v"(p), "v"(v) : "memory");
}
__device__ __forceinline__ void st2_coh(unsigned short* p, unsigned short v) {
    asm volatile("global_store_short %0, %1, off sc0 sc1" :: "v"(p), "v"((unsigned)v) : "memory");
}

// ---- grid barrier (R3-verbatim protocol), split into arrive/wait ----
__device__ __forceinline__ void gbar_arrive(unsigned* bar, unsigned target, int grpId) {
    asm volatile("s_waitcnt vmcnt(0)" ::: "memory");
    __syncthreads();
    if (threadIdx.x == 0) {
        unsigned old = __hip_atomic_fetch_add(bar + 256 + grpId * 16, 1u, __ATOMIC_RELAXED, AGENT);
        if ((old & 15u) == 15u) {
            unsigned old2 = __hip_atomic_fetch_add(bar + 512, 1u, __ATOMIC_RELAXED, AGENT);
            if ((old2 & 15u) == 15u) {
#pragma unroll
                for (int g = 0; g < 16; g++)
                    __hip_atomic_store(bar + g * 16, target, __ATOMIC_RELAXED, AGENT);
            }
        }
    }
}
__device__ __forceinline__ void gbar_wait(unsigned* bar, unsigned target, int grpId) {
    if (threadIdx.x == 0) {
        while (__hip_atomic_load(bar + grpId * 16, __ATOMIC_RELAXED, AGENT) < target)
            __builtin_amdgcn_s_sleep(2);
    }
    __syncthreads();
}
__device__ __forceinline__ void gbar(unsigned* bar, unsigned target, int grpId) {
    gbar_arrive(bar, target, grpId);
    gbar_wait(bar, target, grpId);
}

__device__ __forceinline__ void zero4(float4_ (&a)[4]) {
    float4_ z;
    z[0] = 0.f; z[1] = 0.f; z[2] = 0.f; z[3] = 0.f;
#pragma unroll
    for (int i = 0; i < 4; i++) a[i] = z;
}
__device__ __forceinline__ void copy4(float4_ (&d)[4], const float4_ (&s)[4]) {
#pragma unroll
    for (int i = 0; i < 4; i++) d[i] = s[i];
}

// ---- pipelined chunked staging, plain cached loads ----
#define LD2P(dst, base, OFF) \
    asm volatile("global_load_dwordx2 %0, %1, off offset:" #OFF \
                 : "=v"(dst) : "v"(base))

// 8 chunk-base pointers for one A matrix (chunked [256ch][64b][4u] bf16)
#define BASES8(P, A) \
    const char* P##0 = (const char*)(A) + q * 32768 + (lane >> 4) * 1024 + (lane & 15) * 8; \
    const char* P##1 = P##0 + 4096;  const char* P##2 = P##0 + 8192; \
    const char* P##3 = P##0 + 12288; const char* P##4 = P##0 + 16384; \
    const char* P##5 = P##0 + 20480; const char* P##6 = P##0 + 24576; \
    const char* P##7 = P##0 + 28672;

// 16 loads = one batch-tile (mt): 8 s-blocks x {lo,hi} chunk halves.
#define ISSUE16P(LO, HI, LD, P, O0, O1) \
    do { LD(LO[0], P##0, O0); LD(LO[1], P##1, O0); LD(LO[2], P##2, O0); \
         LD(LO[3], P##3, O0); LD(LO[4], P##4, O0); LD(LO[5], P##5, O0); \
         LD(LO[6], P##6, O0); LD(LO[7], P##7, O0); \
         LD(HI[0], P##0, O1); LD(HI[1], P##1, O1); LD(HI[2], P##2, O1); \
         LD(HI[3], P##3, O1); LD(HI[4], P##4, O1); LD(HI[5], P##5, O1); \
         LD(HI[6], P##6, O1); LD(HI[7], P##7, O1); } while (0)

#define WAITV16(N, LO, HI) \
    asm volatile("s_waitcnt vmcnt(" #N ")" \
                 : "+v"(LO[0]), "+v"(LO[1]), "+v"(LO[2]), "+v"(LO[3]), \
                   "+v"(LO[4]), "+v"(LO[5]), "+v"(LO[6]), "+v"(LO[7]), \
                   "+v"(HI[0]), "+v"(HI[1]), "+v"(HI[2]), "+v"(HI[3]), \
                   "+v"(HI[4]), "+v"(HI[5]), "+v"(HI[6]), "+v"(HI[7]))

#define MFMA8C(LO, HI, BF, ACCI) \
    do { _Pragma("unroll") \
         for (int s_ = 0; s_ < 8; s_++) { \
             u64x2 t_; t_[0] = LO[s_]; t_[1] = HI[s_]; \
             ACCI = __builtin_amdgcn_mfma_f32_16x16x32_bf16( \
                 __builtin_bit_cast(short8, t_), BF[s_], ACCI, 0, 0, 0); } } while (0)

// A chunked [256 chunks][64 b][4 u] bf16. A-frag: m = lane&15 (+16*mt),
// k = q*256 + (lane>>4)*8 + s*32 + j. Chunk pair for (s): bases[s], +512.
// Pipelined: 2-deep rotating 16-load batches, partial vmcnt(16) waits.
// Self-contained: starts at vmcnt==0, ends with WAITV16(0).
__device__ __forceinline__ void mm_pipe(const unsigned short* __restrict__ A,
                                        int q, int lane,
                                        const short8 (&bf)[8], float4_ (&acc)[4]) {
    BASES8(p_, A)
    u64 loA[8], hiA[8], loB[8], hiB[8];
    ISSUE16P(loA, hiA, LD2P, p_, 0, 512);
    ISSUE16P(loB, hiB, LD2P, p_, 128, 640);
    WAITV16(16, loA, hiA); MFMA8C(loA, hiA, bf, acc[0]);
    ISSUE16P(loA, hiA, LD2P, p_, 256, 768);
    WAITV16(16, loB, hiB); MFMA8C(loB, hiB, bf, acc[1]);
    ISSUE16P(loB, hiB, LD2P, p_, 384, 896);
    WAITV16(16, loA, hiA); MFMA8C(loA, hiA, bf, acc[2]);
    WAITV16(0, loB, hiB);  MFMA8C(loB, hiB, bf, acc[3]);
}

// C[m][n]: n = lane&15, m = quad*4+reg  -> gp[(q*64+row)*17+col]
__device__ __forceinline__ void write_parts(float* gp, int q, int lane, float4_ (&acc)[4]) {
    const int col = lane & 15;
    const int rbase = (lane >> 4) * 4;
#pragma unroll
    for (int mt = 0; mt < 4; mt++)
#pragma unroll
        for (int r = 0; r < 4; r++)
            gp[(q * 64 + mt * 16 + rbase + r) * 17 + col] = acc[mt][r];
}

__device__ __forceinline__ float gsum(const float* gp, int b, int c) {
    return gp[(0 * 64 + b) * 17 + c] + gp[(1 * 64 + b) * 17 + c] +
           gp[(2 * 64 + b) * 17 + c] + gp[(3 * 64 + b) * 17 + c];
}

__device__ __forceinline__ short8 packrow(const float* __restrict__ p) {
    short8 r;
#pragma unroll
    for (int j = 0; j < 8; j++) r[j] = (short)f2bf(p[j]);
    return r;
}

__global__ void __launch_bounds__(256, 1)
lstm_core(const float* __restrict__ x, const float* __restrict__ lastp,
          const float* __restrict__ Wih0, const float* __restrict__ Whh0,
          const float* __restrict__ bih0, const float* __restrict__ bhh0,
          const float* __restrict__ Wih1, const float* __restrict__ Whh1,
          const float* __restrict__ bih1, const float* __restrict__ bhh1,
          const float* __restrict__ W1, const float* __restrict__ b1,
          const float* __restrict__ W2, const float* __restrict__ b2,
          float* __restrict__ out, unsigned char* __restrict__ wsb)
{
    const int tid = threadIdx.x;
    const int blk = blockIdx.x;
    const int lane = tid & 63;
    const int q = tid >> 6;          // wave id = K quarter
    const int grpId = blk & 15;
    const int eb = tid >> 2;         // epilogue: batch row
    const int eu = tid & 3;          // epilogue: unit-within-block
    const int D_ = blk * 4 + eu;     // global hidden unit / fc dim

    unsigned* bar = (unsigned*)wsb;
    // rotating regions in static device memory: 97 + 97 + 32 x 131072 B
    unsigned short* h0base = (unsigned short*)gws_static;
    unsigned short* h1base = h0base + (size_t)97 * 65536;
    unsigned short* relub  = h0base + (size_t)194 * 65536;

    auto h0p = [&](int g) -> unsigned short* {
        return h0base + (size_t)(g + 1) * 65536;
    };
    auto h1p = [&](int g) -> unsigned short* {
        return h1base + (size_t)(g + 1) * 65536;
    };

    __shared__ float gparts[4 * 64 * 17];
    __shared__ float xlds[2][64 * 21];
    __shared__ float wih0l[16 * 20];

    // ---- barrier area init (block 0) ----
    if (blk == 0 && tid == 0) {
        for (int g = 0; g < 16; g++) {
            __hip_atomic_store(bar + g * 16, 0u, __ATOMIC_RELAXED, AGENT);
            __hip_atomic_store(bar + 256 + g * 16, 0u, __ATOMIC_RELAXED, AGENT);
        }
        __hip_atomic_store(bar + 512, 0u, __ATOMIC_RELAXED, AGENT);
        __hip_atomic_store(bar + 544, 0x1357BDFu, __ATOMIC_RELEASE, AGENT);
    }

    // ---- prologue: stage x[0] into xlds[0] (drained by initial gbar) ----
    for (int i = tid; i < 1280; i += 256) {
        const int bb = i / 20, mm = i - bb * 20;
        xlds[0][bb * 21 + mm] = x[bb * 1280 + mm];
    }

    // ---- per-lane B-fragment preload (bf16, RNE) ----
    const int n_ = lane & 15;
    const int gq_ = n_ >> 2, uu_ = n_ & 3;
    const int growL = gq_ * 1024 + blk * 4 + uu_;   // gate row for this col
    const int kq = (q << 8) + ((lane >> 4) << 3);

    short8 whh0f[8], wih1f[8], whh1f[8], wfusedf[8], wfcf[8];
#pragma unroll
    for (int s = 0; s < 8; s++) {
        const int k = kq + s * 32;
        whh0f[s] = packrow(Whh0 + growL * 1024 + k);
        wih1f[s] = packrow(Wih1 + growL * 1024 + k);
        whh1f[s] = packrow(Whh1 + growL * 1024 + k);
        { // Wfused[row][k] = sum_m Wih0[row][m] * W2[m][k]
            float a8[8] = {0.f, 0.f, 0.f, 0.f, 0.f, 0.f, 0.f, 0.f};
            for (int m = 0; m < 20; m++) {
                float wv = Wih0[growL * 20 + m];
                const float* w2p = W2 + m * 1024 + k;
#pragma unroll
                for (int j = 0; j < 8; j++) a8[j] += wv * w2p[j];
            }
            short8 r;
#pragma unroll
            for (int j = 0; j < 8; j++) r[j] = (short)f2bf(a8[j]);
            wfusedf[s] = r;
        }
        { // fc B: cols 0-3 = W1h rows, cols 4-7 = Wskip rows, 8-15 = 0
            short8 r;
            if (n_ < 4) {
                r = packrow(W1 + (blk * 4 + n_) * 1040 + k);
            } else if (n_ < 8) {
                const int D = blk * 4 + (n_ - 4);
                float a8[8] = {0.f, 0.f, 0.f, 0.f, 0.f, 0.f, 0.f, 0.f};
                for (int g2 = 0; g2 < 16; g2++) {
                    const int m = 5 * (g2 >> 2) + (g2 & 3);
                    float wv = W1[D * 1040 + 1024 + g2] * 0.01f;
                    const float* w2p = W2 + m * 1024 + k;
#pragma unroll
                    for (int j = 0; j < 8; j++) a8[j] += wv * w2p[j];
                }
#pragma unroll
                for (int j = 0; j < 8; j++) r[j] = (short)f2bf(a8[j]);
            } else {
#pragma unroll
                for (int j = 0; j < 8; j++) r[j] = 0;
            }
            wfcf[s] = r;
        }
    }

    // ---- per-thread constants (epilogue mapping: eb = tid>>2, eu = tid&3) ----
    float bias0g[4], bias1g[4], cgv[4];
#pragma unroll
    for (int g = 0; g < 4; g++) {
        const int row = g * 1024 + D_;
        bias0g[g] = bih0[row] + bhh0[row];
        bias1g[g] = bih1[row] + bhh1[row];
        float s = 0.f;
        for (int m = 0; m < 20; m++) s += Wih0[row * 20 + m] * b2[m];
        cgv[g] = s;
    }
    const float fcb = b1[D_];
    float cbv = 0.f, ustate = 0.f;
    for (int g2 = 0; g2 < 16; g2++) {
        const float w1v = W1[D_ * 1040 + 1024 + g2];
        cbv += b2[5 * (g2 >> 2) + (g2 & 3)] * w1v * 0.01f;
        ustate += lastp[eb * 16 + g2] * w1v;   // u(0) = lp0 @ W1lp^T
    }
    float c0v = 0.f, c1v = 0.f;

    if (tid < 16) { // Wih0 rows for x-path (fp32, exact)
        const int row = (tid >> 2) * 1024 + blk * 4 + (tid & 3);
        for (int m = 0; m < 20; m++) wih0l[tid * 20 + m] = Wih0[row * 20 + m];
    }
    // zero initial h state (g = -1); chunked: chunk blk, batch tid
    if (tid < 64) {
        st8_coh(h0p(-1) + blk * 256 + tid * 4, 0ull);
        st8_coh(h1p(-1) + blk * 256 + tid * 4, 0ull);
    }

    if (tid == 0) {
        while (__hip_atomic_load(bar + 544, __ATOMIC_RELAXED, AGENT) != 0x1357BDFu)
            __builtin_amdgcn_s_sleep(2);
    }
    unsigned tgt = 1;
    gbar(bar, tgt++, grpId);

    // ---- direct per-thread publish: thread's element = chunk blk, idx tid ----
    auto publish = [&](unsigned short* dst, unsigned short val) {
        st2_coh(dst + blk * 256 + tid, val);
    };

    // L0 epilogue: gparts -> gates -> c0 -> publish. pf >= 0: prefetch x[pf].
    auto l0_finish = [&](float4_ (&acc)[4], unsigned short* h0dst, int xt, int pf) {
        write_parts(gparts, q, lane, acc);
        __syncthreads();
        if (pf >= 0) {  // stage x[pf] into the other buffer; drains at next gbar
            for (int i = tid; i < 1280; i += 256) {
                const int bb = i / 20, mm = i - bb * 20;
                xlds[pf & 1][bb * 21 + mm] = x[bb * 1280 + pf * 20 + mm];
            }
        }
        float gv[4];
#pragma unroll
        for (int g = 0; g < 4; g++) gv[g] = gsum(gparts, eb, g * 4 + eu) + bias0g[g];
        if (xt >= 0) {
#pragma unroll
            for (int g = 0; g < 4; g++) {
                float s = 0.f;
                const float* wr = &wih0l[(g * 4 + eu) * 20];
                const float* xr = &xlds[xt & 1][eb * 21];
                for (int m = 0; m < 20; m++) s += xr[m] * wr[m];
                gv[g] += s;
            }
        } else {
#pragma unroll
            for (int g = 0; g < 4; g++) gv[g] += cgv[g];
        }
        const float iv = sigm(gv[0]), fv = sigm(gv[1]);
        const float gt = tanhf_(gv[2]), ov = sigm(gv[3]);
        c0v = fv * c0v + iv * gt;
        publish(h0dst, f2bf(ov * tanhf_(c0v)));
    };

    auto l1_finish = [&](float4_ (&acc)[4], unsigned short* h1dst) {
        write_parts(gparts, q, lane, acc);
        __syncthreads();
        float gv[4];
#pragma unroll
        for (int g = 0; g < 4; g++) gv[g] = gsum(gparts, eb, g * 4 + eu) + bias1g[g];
        const float iv = sigm(gv[0]), fv = sigm(gv[1]);
        const float gt = tanhf_(gv[2]), ov = sigm(gv[3]);
        c1v = fv * c1v + iv * gt;
        publish(h1dst, f2bf(ov * tanhf_(c1v)));
    };

    auto fc_finish = [&](int t, float4_ (&acc1)[4], float4_ (&acc2)[4]) {
        const int col = lane & 15;
        const int rbase = (lane >> 4) * 4;
        if (col < 8) {
#pragma unroll
            for (int mt = 0; mt < 4; mt++)
#pragma unroll
                for (int r = 0; r < 4; r++) {
                    const float v = (col < 4) ? acc1[mt][r] : acc2[mt][r];
                    gparts[(q * 64 + mt * 16 + rbase + r) * 17 + col] = v;
                }
        }
        __syncthreads();
        const float s1 = gsum(gparts, eb, eu);
        if (t > 0) ustate += gsum(gparts, eb, 4 + eu) + cbv;
        const float rv = fmaxf(s1 + ustate + fcb, 0.f);
        publish(relub + t * 65536, f2bf(rv));
    };

    // ---- encoder: 64 steps x {L0, barrier, L1} (post-L1 barrier elided) ----
    for (int g = 0; g < 64; g++) {
        float4_ acc[4];
        zero4(acc);
        mm_pipe(h0p(g - 1), q, lane, whh0f, acc);
        l0_finish(acc, h0p(g), g, (g < 63) ? g + 1 : -1);
        gbar(bar, tgt, grpId); tgt++;
        zero4(acc);
        mm_pipe(h0p(g), q, lane, wih1f, acc);
        mm_pipe(h1p(g - 1), q, lane, whh1f, acc);
        l1_finish(acc, h1p(g));
    }

    // ---- decoder: 32 steps x {L0, b, L1, b, FC, b} with fuzzy barriers ----
    float4_ haccL0[4];   // hoisted Whh0 @ h0[t]   (for L0(t+1); order: first)
    float4_ hacc2[4];    // hoisted Wskip @ relu[t-1] (FC acc2; separate acc)
    bool haveL0 = false;
    for (int t = 0; t < 32; t++) {
        const int g = 64 + t;
        unsigned short* rp = (t > 0) ? (relub + (t - 1) * 65536) : nullptr;

        // ---- L0 slot ----
        float4_ acc[4];
        if (haveL0) {
            copy4(acc, haccL0);                 // Whh0 @ h0[g-1] (hoisted)
        } else {
            zero4(acc);
            mm_pipe(h0p(g - 1), q, lane, whh0f, acc);
        }
        if (rp) mm_pipe(rp, q, lane, wfusedf, acc);   // order: whh0 then wfused ✓
        l0_finish(acc, h0p(g), (t == 0) ? 63 : -1, -1);
        gbar_arrive(bar, tgt, grpId);
        if (rp) {   // hoist FC's acc2 = Wskip @ relu[t-1] (2 barriers old, L2-hot)
            zero4(hacc2);
            mm_pipe(rp, q, lane, wfcf, hacc2);
        }
        gbar_wait(bar, tgt, grpId); tgt++;

        // ---- L1 slot ---- (both mm fresh; accumulation order preserved)
        zero4(acc);
        mm_pipe(h0p(g), q, lane, wih1f, acc);
        mm_pipe(h1p(g - 1), q, lane, whh1f, acc);
        l1_finish(acc, h1p(g));
        gbar_arrive(bar, tgt, grpId);
        gbar_wait(bar, tgt, grpId); tgt++;

        // ---- FC slot ----
        float4_ acc1[4], acc2[4];
        zero4(acc1);
        mm_pipe(h1p(g), q, lane, wfcf, acc1);
        if (rp) copy4(acc2, hacc2); else zero4(acc2);
        fc_finish(t, acc1, acc2);
        gbar_arrive(bar, tgt, grpId);
        if (t < 31) {   // hoist next L0's Whh0 @ h0[g] (2 barriers old, L2-hot)
            zero4(haccL0);
            mm_pipe(h0p(g), q, lane, whh0f, haccL0);
            haveL0 = true;
        }
        gbar_wait(bar, tgt, grpId); tgt++;
    }

    // ---- final: pred[t] = relu[t] @ W2^T + b2 -> out[b][t][m] ----
    {
        const int pj = tid >> 5;   // 8 (t,b) pairs per block
        const int m = tid & 31;
        if (m < 20) {
            const int pidx = blk * 8 + pj;
            const int tt = pidx >> 6, bb = pidx & 63;
            const unsigned short* rr = relub + tt * 65536;  // chunked region
            const float* w = W2 + m * 1024;
            float acc = 0.f;
            for (int c = 0; c < 256; c++) {
                const u64 v8 = *(const u64*)(rr + c * 256 + bb * 4);
#pragma unroll
                for (int j = 0; j < 4; j++)
                    acc += bf2f((unsigned short)(v8 >> (16 * j))) * w[c * 4 + j];
            }
            out[bb * 640 + tt * 20 + m] = acc + b2[m];
        }
    }
}

extern "C" void kernel_launch(void* const* d_in, const int* in_sizes, int n_in,
                              void* d_out, int out_size, void* d_ws, size_t ws_size,
                              hipStream_t stream) {
    (void)in_sizes; (void)n_in; (void)out_size; (void)ws_size;
    const float* x     = (const float*)d_in[0];
    const float* lastp = (const float*)d_in[1];
    const float* Wih0  = (const float*)d_in[2];
    const float* Whh0  = (const float*)d_in[3];
    const float* bih0  = (const float*)d_in[4];
    const float* bhh0  = (const float*)d_in[5];
    const float* Wih1  = (const float*)d_in[6];
    const float* Whh1  = (const float*)d_in[7];
    const float* bih1  = (const float*)d_in[8];
    const float* bhh1  = (const float*)d_in[9];
    const float* W1    = (const float*)d_in[10];
    const float* b1    = (const float*)d_in[11];
    const float* W2    = (const float*)d_in[12];
    const float* b2    = (const float*)d_in[13];
    float* out = (float*)d_out;
    unsigned char* ws = (unsigned char*)d_ws;

    void* args[] = {&x, &lastp, &Wih0, &Whh0, &bih0, &bhh0, &Wih1, &Whh1,
                    &bih1, &bhh1, &W1, &b1, &W2, &b2, &out, &ws};
    hipError_t err = hipLaunchCooperativeKernel((const void*)lstm_core,
                                                dim3(256), dim3(256), args, 0, stream);
    if (err != hipSuccess) {
        hipLaunchKernelGGL(lstm_core, dim3(256), dim3(256), 0, stream,
                           x, lastp, Wih0, Whh0, bih0, bhh0, Wih1, Whh1,
                           bih1, bhh1, W1, b1, W2, b2, out, ws);
    }
}